// Round 8
// baseline (92.339 us; speedup 1.0000x reference)
//
#include <hip/hip_runtime.h>

#define SEQ_L 4096
#define BATCH 4
#define DMODEL 512
#define STRIPE 512          // geometric band bound (mean true band ~225)

typedef float f4 __attribute__((ext_vector_type(4)));

#define SCG  (BATCH * SEQ_L * (SEQ_L / 4) / 64)        // 262144 score groups
#define EMBG (BATCH * SEQ_L * (2 * DMODEL / 4) / 64)   // 65536 emb groups
#define TOTG (SCG + EMBG)                              // 327680
#define BBLK 2048
#define WB   (BBLK * 4)                                // 8192 waves, 40 iters/wave

// ---------------------------------------------------------------------------
// A: per-row (ti, 1/denom) into ws. 1024 waves x 16 rows.
// Math: t=time/200; s=100*exp(-((ti-tj)^2)^2*40000); row max exactly 100;
// denom = sum_{j in [ls,i]} exp(s-100); terms below ls are < 4e-44 (dropped).
// ---------------------------------------------------------------------------
__global__ __launch_bounds__(256) void param_kernel(const float* __restrict__ tm,
                                                    float2* __restrict__ ws) {
    const int lane = threadIdx.x & 63;
    const int gw = blockIdx.x * 4 + (threadIdx.x >> 6);   // 0..1023
    const float inv200 = 1.0f / 200.0f;
    for (int r = 0; r < 16; ++r) {
        const int row = gw * 16 + r;
        const int b = row >> 12, i = row & (SEQ_L - 1);
        const float* tb = tm + b * SEQ_L;
        const float ti = tb[i] * inv200;
        int ls = i - STRIPE; if (ls < 0) ls = 0;
        ls &= ~31;
        float sum = 0.0f;
        for (int j = ls + lane; j <= i; j += 64) {
            float d = ti - tb[j] * inv200;
            float d2 = d * d;
            float s = 100.0f * __expf(-(d2 * d2) * 40000.0f);
            sum += __expf(s - 100.0f);
        }
        #pragma unroll
        for (int off = 1; off < 64; off <<= 1) sum += __shfl_xor(sum, off, 64);
        if (lane == 0) ws[row] = make_float2(ti, 1.0f / sum);
    }
}

// ---------------------------------------------------------------------------
// B: fill-shaped linear sweep of the whole 335 MB output. Group G (64 lanes x
// 16 B = 1 KB, wave-uniform row) at G = k*WB + w -> active window across the
// grid is ~8 MB marching forward, like rocclr fillBuffer. 15/16 score groups
// are geometric zeros; band groups read ws (128 KB) + tm (64 KB) from L2.
// ---------------------------------------------------------------------------
__global__ __launch_bounds__(256) void sweep_kernel(const int* __restrict__ et,
                                                    const float* __restrict__ tm,
                                                    const float* __restrict__ tab,
                                                    const float2* __restrict__ ws,
                                                    float* __restrict__ out) {
    const int lane = threadIdx.x & 63;
    const int w = blockIdx.x * 4 + (threadIdx.x >> 6);
    f4* base = (f4*)out;
    const f4 z = {0.f, 0.f, 0.f, 0.f};
    const float inv200 = 1.0f / 200.0f;

    for (int G = w; G < TOTG; G += WB) {
        f4 v = z;
        if (G < SCG) {
            // ---- scores chunk ----
            const int row = G >> 4;                 // wave-uniform
            const int c0 = (G & 15) << 6;
            const int i = row & (SEQ_L - 1);
            const int b = row >> 12;
            int ls = i - STRIPE; if (ls < 0) ls = 0;
            ls &= ~31;
            const int ls4 = ls >> 2;
            const int rs4 = ((i & ~31) + 32) >> 2;
            if (c0 + 64 > ls4 && c0 < rs4) {        // group intersects stripe
                const int c = c0 + lane;
                if (c >= ls4 && c < rs4) {
                    const float2 pr = ws[row];      // (ti, inv_denom)
                    const f4 tv = ((const f4*)(tm + b * SEQ_L))[c];
                    #pragma unroll
                    for (int q = 0; q < 4; ++q) {
                        const int jj = 4 * c + q;
                        float d = pr.x - tv[q] * inv200;
                        float d2 = d * d;
                        float s = 100.0f * __expf(-(d2 * d2) * 40000.0f);
                        float p = __expf(s - 100.0f) * pr.y;
                        v[q] = (jj <= i) ? p : 0.0f;
                    }
                }
            }
        } else {
            // ---- embedding chunk ----
            const int eg = G - SCG;
            const int row = eg >> 2;                // (b*L + l), wave-uniform
            const int c = ((eg & 3) << 6) + lane;   // f4 col in [0,256)
            if (c < 128) {                          // temporal half
                const float time = tm[row];
                const float C2 = -13.287712379549449f / 512.0f;  // -log2(1e4)/512
                const int k0 = 4 * c;
                const float ipA = exp2f(C2 * (float)k0);
                const float ipB = exp2f(C2 * (float)(k0 + 2));
                const float a = time * ipA, bp = time * ipB;
                v[0] = __sinf(a);  v[1] = __cosf(a);
                v[2] = __sinf(bp); v[3] = __cosf(bp);
            } else {                                // type-embedding half
                const f4 e = *(const f4*)(tab + et[row] * DMODEL + (4 * c - DMODEL));
                v = e * 22.627416997969522f;        // sqrt(512)
            }
        }
        base[(size_t)G * 64 + lane] = v;
    }
}

extern "C" void kernel_launch(void* const* d_in, const int* in_sizes, int n_in,
                              void* d_out, int out_size, void* d_ws, size_t ws_size,
                              hipStream_t stream) {
    const int*   event_type = (const int*)d_in[0];
    const float* event_time = (const float*)d_in[1];
    const float* emb_table  = (const float*)d_in[2];

    param_kernel<<<256, 256, 0, stream>>>(event_time, (float2*)d_ws);
    sweep_kernel<<<BBLK, 256, 0, stream>>>(event_type, event_time, emb_table,
                                           (const float2*)d_ws, (float*)d_out);
}

// Round 9
// 65.165 us; speedup vs baseline: 1.4170x; 1.4170x over previous
//
#include <hip/hip_runtime.h>

#define SEQ_L 4096
#define BATCH 4
#define DMODEL 512
#define CUT 0.055f          // normalized gap beyond which exp(s-100) < 5e-14

typedef float f4 __attribute__((ext_vector_type(4)));

#define BAND_BLOCKS 1024    // 16 score rows each
#define EMB_BLOCKS  2048    // 8 emb rows each
#define NBLK (BAND_BLOCKS + EMB_BLOCKS)   // 3072, band = every 3rd block

// After hipMemsetAsync zeroes the scores buffer, this kernel writes only:
//   - scores band: per row i, chunks [ (jlo>>2)&~7 , i>>2 ] (~1.1 KB/row).
//     Math: t=time/200; s=100*exp(-((ti-tj)^2)^2*40000); row max exactly 100
//     (diagonal); softmax = exp(s-100)*inv_denom; entries below jlo underflow
//     to ~0 exactly like the reference; entries j>i masked to exact 0 (but
//     those lie beyond ce except in-chunk tail, handled by mask).
//   - embedding: [B,L,2D] = [sin/cos temporal | table*sqrt(512)].
__global__ __launch_bounds__(256) void band_emb_kernel(const int* __restrict__ et,
                                                       const float* __restrict__ tm,
                                                       const float* __restrict__ tab,
                                                       float* __restrict__ scores,
                                                       float* __restrict__ emb) {
    const int bid = blockIdx.x;

    if (bid % 3 == 2) {
        // ---------------- scores band ----------------
        __shared__ float ts[SEQ_L];
        const int sidx = bid / 3;              // 0..1023
        const int b  = sidx >> 8;              // 256 blocks per batch
        const int i0 = (sidx & 255) * 16;

        const f4* tb4 = (const f4*)(tm + b * SEQ_L);
        f4* ts4 = (f4*)ts;
        #pragma unroll
        for (int q = 0; q < 4; ++q) {
            int j = threadIdx.x + q * 256;
            ts4[j] = tb4[j] * (1.0f / 200.0f);
        }
        __syncthreads();

        const int wave = threadIdx.x >> 6;
        const int lane = threadIdx.x & 63;
        const int ibase = i0 + wave * 4;

        int jlo;
        {   // binary search once per wave
            const float tc = ts[ibase] - CUT;
            int lo = 0, hi = ibase;
            while (lo < hi) {
                int mid = (lo + hi) >> 1;
                if (ts[mid] < tc) lo = mid + 1; else hi = mid;
            }
            jlo = lo;
        }

        for (int r = 0; r < 4; ++r) {
            const int i = ibase + r;
            const float ti = ts[i];
            const float tc = ti - CUT;
            for (;;) {  // ballot monotone advance (sorted => prefix predicate)
                int idx = jlo + lane; if (idx > SEQ_L - 1) idx = SEQ_L - 1;
                int cnt = __popcll(__ballot(ts[idx] < tc));
                jlo += cnt;
                if (cnt < 64) break;
            }

            float sum = 0.0f;
            for (int j = jlo + lane; j <= i; j += 64) {
                float d = ti - ts[j];
                float d2 = d * d;
                float s = 100.0f * __expf(-(d2 * d2) * 40000.0f);
                sum += __expf(s - 100.0f);
            }
            #pragma unroll
            for (int off = 1; off < 64; off <<= 1) sum += __shfl_xor(sum, off, 64);
            const float inv = 1.0f / sum;

            const int cs = (jlo >> 2) & ~7;    // 128B-aligned band start
            const int ce = i >> 2;
            f4* out4 = (f4*)(scores + ((size_t)(b * SEQ_L + i)) * SEQ_L);
            for (int c = cs + lane; c <= ce; c += 64) {
                f4 tv = ts4[c];
                f4 v;
                #pragma unroll
                for (int q = 0; q < 4; ++q) {
                    const int jj = 4 * c + q;
                    float d = ti - tv[q];
                    float d2 = d * d;
                    float s = 100.0f * __expf(-(d2 * d2) * 40000.0f);
                    float p = __expf(s - 100.0f) * inv;
                    v[q] = (jj <= i) ? p : 0.0f;
                }
                out4[c] = v;
            }
        }
    } else {
        // ---------------- embedding ----------------
        const int t = threadIdx.x;
        const bool temporal = t < 128;

        float ipA = 0.0f, ipB = 0.0f;
        if (temporal) {
            const float c = -13.287712379549449f / 256.0f;   // -log2(10000)/256
            ipA = exp2f(c * (float)(2 * t));
            ipB = exp2f(c * (float)(2 * t + 1));
        }
        const int ecol = (t - 128) * 4;

        const int eidx = (bid / 3) * 2 + (bid % 3);          // 0..2047
        const int bl0 = eidx * 8;
        #pragma unroll
        for (int r = 0; r < 8; ++r) {
            const int bl = bl0 + r;
            f4 v;
            if (temporal) {
                const float time = tm[bl];
                const float a = time * ipA;
                const float bp = time * ipB;
                v[0] = __sinf(a);  v[1] = __cosf(a);
                v[2] = __sinf(bp); v[3] = __cosf(bp);
            } else {
                f4 e = *(const f4*)(tab + et[bl] * DMODEL + ecol);
                v = e * 22.627416997969522f;                 // sqrt(512)
            }
            ((f4*)(emb + (size_t)bl * 2 * DMODEL))[t] = v;
        }
    }
}

extern "C" void kernel_launch(void* const* d_in, const int* in_sizes, int n_in,
                              void* d_out, int out_size, void* d_ws, size_t ws_size,
                              hipStream_t stream) {
    const int*   event_type = (const int*)d_in[0];
    const float* event_time = (const float*)d_in[1];
    const float* emb_table  = (const float*)d_in[2];

    float* scores = (float*)d_out;
    float* emb    = scores + (size_t)BATCH * SEQ_L * SEQ_L;

    // 80% of output bytes via the proven 6.9 TB/s fill path.
    hipMemsetAsync(scores, 0, (size_t)BATCH * SEQ_L * SEQ_L * sizeof(float), stream);

    band_emb_kernel<<<NBLK, 256, 0, stream>>>(
        event_type, event_time, emb_table, scores, emb);
}